// Round 3
// baseline (924.033 us; speedup 1.0000x reference)
//
#include <hip/hip_runtime.h>
#include <math.h>

// AnswerPointerNetwork: H=256, B=64, LP=2048, LQ=64, fp32 in/out.
// R3: barrier-free MFMA GEMM — B pre-permuted to fragment-direct global layout
//     (register loads from L2, no LDS), A fragments loaded direct from global
//     (16 rows x 128B sector-complete), fp32->bf16 via v_perm packing.
//     Small kernels fused: softmax_rq+u1, gru(gi,gh,gates), vectorized ct.

constexpr int Bn   = 64;
constexpr int Hn   = 256;
constexpr int D2H  = 512;
constexpr int LPn  = 2048;
constexpr int LQn  = 64;

typedef __attribute__((ext_vector_type(8))) short bf16x8;
typedef __attribute__((ext_vector_type(4))) float f32x4;

__device__ inline float waveAllSum(float v) {
  #pragma unroll
  for (int o = 32; o > 0; o >>= 1) v += __shfl_xor(v, o, 64);
  return v;
}
__device__ inline float waveAllMax(float v) {
  #pragma unroll
  for (int o = 32; o > 0; o >>= 1) v = fmaxf(v, __shfl_xor(v, o, 64));
  return v;
}

__device__ inline short f2bf_rtne(float f) {
  union { float f; unsigned u; } v; v.f = f;
  unsigned r = v.u + 0x7FFF + ((v.u >> 16) & 1);
  return (short)(r >> 16);
}

// pack two fp32 -> packed bf16 pair (round-to-nearest, ties away) in 3 VALU
__device__ inline unsigned pk2(float lo, float hi) {
  union { float f; unsigned u; } a, b; a.f = lo; b.f = hi;
  return __builtin_amdgcn_perm(b.u + 0x8000u, a.u + 0x8000u, 0x07060302u);
}
__device__ inline bf16x8 cvt8(f32x4 a0, f32x4 a1) {
  union { unsigned u[4]; bf16x8 v; } r;
  r.u[0] = pk2(a0[0], a0[1]);
  r.u[1] = pk2(a0[2], a0[3]);
  r.u[2] = pk2(a1[0], a1[1]);
  r.u[3] = pk2(a1[2], a1[3]);
  return r.v;
}

// -------- W -> fragment-direct permuted bf16 layout --------
// slot s = ((wj*8 + k0i)*2 + h)*64 + l; holds W[n][k..k+8), n=w*64+j*16+(l&15),
// k=k0i*64+h*32+(l>>4)*8.  GEMM wave loads one dwordx4 per fragment.
__global__ __launch_bounds__(256) void k_wcvt(const float* __restrict__ WQu,
                                              const float* __restrict__ WPh,
                                              short* __restrict__ q2,
                                              short* __restrict__ p2) {
  int s = blockIdx.x * 256 + threadIdx.x;  // 0..32767
  const float* W; short* D; int slot;
  if (s < 16384) { W = WQu; D = q2; slot = s; }
  else           { W = WPh; D = p2; slot = s - 16384; }
  int l    = slot & 63;
  int rest = slot >> 6;          // ((w*4+j)*8 + k0i)*2 + h
  int h    = rest & 1;
  int k0i  = (rest >> 1) & 7;
  int wj   = rest >> 4;          // 0..15
  int l15  = l & 15, quad = l >> 4;
  int n = (wj >> 2) * 64 + (wj & 3) * 16 + l15;
  int k = k0i * 64 + h * 32 + quad * 8;
  f32x4 f0 = *(const f32x4*)&W[n * 512 + k];
  f32x4 f1 = *(const f32x4*)&W[n * 512 + k + 4];
  bf16x8 o;
  o[0] = f2bf_rtne(f0[0]); o[1] = f2bf_rtne(f0[1]);
  o[2] = f2bf_rtne(f0[2]); o[3] = f2bf_rtne(f0[3]);
  o[4] = f2bf_rtne(f1[0]); o[5] = f2bf_rtne(f1[1]);
  o[6] = f2bf_rtne(f1[2]); o[7] = f2bf_rtne(f1[3]);
  *(bf16x8*)&D[slot * 8] = o;
}

// -------- tiny: v2 = VQr @ WQv_W.T + WQv_b --------
__global__ __launch_bounds__(256) void k_v2(const float* __restrict__ VQr,
                                            const float* __restrict__ WQv_W,
                                            const float* __restrict__ WQv_b,
                                            float* __restrict__ v2) {
  __shared__ float s[256];
  int t = threadIdx.x;
  s[t] = VQr[t];
  __syncthreads();
  float acc = WQv_b[t];
  for (int k = 0; k < 256; ++k) acc += s[k] * WQv_W[t * 256 + k];
  v2[t] = acc;
}

// -------- barrier-free fused bf16 MFMA GEMM + tanh-dot epilogue --------
// C[m][n] = sum_k A[m][k]*W[n][k] + bias[n]  (A fp32 global, W permuted bf16)
// block = 64 rows x 256 cols, 4 waves (wave w owns cols w*64..w*64+63).
// sOut[b*sstride + blockIdx.x] = sum_n tanh(C[m]+u)*vt, b = m & 63.
__global__ __launch_bounds__(256, 3) void k_mfma_fused(
    const float* __restrict__ A,
    const short* __restrict__ Wb2,
    const float* __restrict__ bias,
    const float* __restrict__ u,
    const float* __restrict__ vt,
    float* __restrict__ C,
    float* __restrict__ sOut,
    int ustride, int sstride)
{
  __shared__ float sred[4][64];
  const int tid  = threadIdx.x;
  const int w    = tid >> 6;
  const int l    = tid & 63;
  const int l15  = l & 15;
  const int quad = l >> 4;
  const long bm  = (long)blockIdx.x * 64;

  f32x4 acc[4][4];
  #pragma unroll
  for (int i = 0; i < 4; ++i)
    #pragma unroll
    for (int j = 0; j < 4; ++j)
      acc[i][j] = (f32x4)0.f;

  const float* arow[4];
  #pragma unroll
  for (int i = 0; i < 4; ++i)
    arow[i] = A + (size_t)(bm + i * 16 + l15) * 512 + quad * 8;
  const short* bptr = Wb2 + (size_t)w * 4 * 8192 + l * 8;

  for (int k0i = 0; k0i < 8; ++k0i) {
    const int k0 = k0i * 64;
    // A: 16 independent dwordx4 loads (16 rows x 128B contiguous pieces)
    f32x4 a0[4][2], a1[4][2];
    #pragma unroll
    for (int i = 0; i < 4; ++i)
      #pragma unroll
      for (int h = 0; h < 2; ++h) {
        const float* p = arow[i] + k0 + h * 32;
        a0[i][h] = *(const f32x4*)p;
        a1[i][h] = *(const f32x4*)(p + 4);
      }
    // B: 8 fragment-direct dwordx4 loads (L2-resident W)
    bf16x8 bfr[2][4];
    #pragma unroll
    for (int h = 0; h < 2; ++h)
      #pragma unroll
      for (int j = 0; j < 4; ++j)
        bfr[h][j] = *(const bf16x8*)(bptr + j * 8192 + k0i * 1024 + h * 512);
    #pragma unroll
    for (int h = 0; h < 2; ++h) {
      bf16x8 af[4];
      #pragma unroll
      for (int i = 0; i < 4; ++i) af[i] = cvt8(a0[i][h], a1[i][h]);
      #pragma unroll
      for (int i = 0; i < 4; ++i)
        #pragma unroll
        for (int j = 0; j < 4; ++j)
          acc[i][j] = __builtin_amdgcn_mfma_f32_16x16x32_bf16(af[i], bfr[h][j], acc[i][j], 0, 0, 0);
    }
  }

  // epilogue: bias, optional C store, fused tanh-dot over n
  float srow[4][4];
  #pragma unroll
  for (int i = 0; i < 4; ++i) {
    #pragma unroll
    for (int r = 0; r < 4; ++r) {
      const int row = i * 16 + quad * 4 + r;   // == b
      float s_acc = 0.f;
      #pragma unroll
      for (int j = 0; j < 4; ++j) {
        const int n = w * 64 + j * 16 + l15;
        float val = acc[i][j][r] + bias[n];
        if (C) C[(bm + row) * 256 + n] = val;
        s_acc += tanhf(val + u[ustride * row + n]) * vt[row * 256 + n];
      }
      srow[i][r] = s_acc;
    }
  }
  #pragma unroll
  for (int off = 1; off < 16; off <<= 1)
    #pragma unroll
    for (int i = 0; i < 4; ++i)
      #pragma unroll
      for (int r = 0; r < 4; ++r)
        srow[i][r] += __shfl_xor(srow[i][r], off, 64);
  if (l15 == 0)
    #pragma unroll
    for (int i = 0; i < 4; ++i)
      #pragma unroll
      for (int r = 0; r < 4; ++r)
        sred[w][i * 16 + quad * 4 + r] = srow[i][r];
  __syncthreads();
  if (tid < 64)
    sOut[(size_t)tid * sstride + blockIdx.x] =
        sred[0][tid] + sred[1][tid] + sred[2][tid] + sred[3][tid];
}

// -------- softmax(sQ) -> rQ -> u1, one block per b --------
__global__ __launch_bounds__(256) void k_rq_u1(const float* __restrict__ sQ,
                                               const float* __restrict__ quesEnc,
                                               const float* __restrict__ Wah,
                                               const float* __restrict__ Wah_b,
                                               float* __restrict__ rQ,
                                               float* __restrict__ u1) {
  int b = blockIdx.x, tid = threadIdx.x;
  __shared__ float s_a[LQn];
  __shared__ float s_r[D2H];
  if (tid < 64) {
    float s = sQ[b * LQn + tid];
    float m = waveAllMax(s);
    float e = expf(s - m);
    float sum = waveAllSum(e);
    s_a[tid] = e / sum;
  }
  __syncthreads();
  #pragma unroll
  for (int rep = 0; rep < 2; ++rep) {
    int d = tid + rep * 256;
    float acc = 0.f;
    for (int q = 0; q < LQn; ++q)
      acc += s_a[q] * quesEnc[(size_t)(q * Bn + b) * D2H + d];
    s_r[d] = acc;
    rQ[b * D2H + d] = acc;
  }
  __syncthreads();
  // u1[b][n] = Wah[n] . rQ[b] + Wah_b[n]
  float accu = Wah_b[tid];
  const float* wr = Wah + (size_t)tid * 512;
  for (int k4 = 0; k4 < 128; ++k4) {
    f32x4 wv = *(const f32x4*)&wr[k4 * 4];
    f32x4 rv = *(const f32x4*)&s_r[k4 * 4];
    accu += wv[0] * rv[0] + wv[1] * rv[1] + wv[2] * rv[2] + wv[3] * rv[3];
  }
  u1[b * Hn + tid] = accu;
}

// -------- sP[b][p] = sum_h tanh(passP[p,b,h]+u[b,h])*Vt2[b,h] --------
__global__ __launch_bounds__(256) void k_sp(const float* __restrict__ passP,
                                            const float* __restrict__ u,
                                            const float* __restrict__ Vt2,
                                            float* __restrict__ sP) {
  int flat = blockIdx.x * 4 + (threadIdx.x >> 6);
  int lane = threadIdx.x & 63;
  int b = flat & (Bn - 1);
  int p = flat >> 6;
  float4 v  = *(const float4*)&passP[(size_t)flat * Hn + lane * 4];
  float4 uu = *(const float4*)&u[b * Hn + lane * 4];
  float4 vt = *(const float4*)&Vt2[b * Hn + lane * 4];
  float s = tanhf(v.x + uu.x) * vt.x + tanhf(v.y + uu.y) * vt.y +
            tanhf(v.z + uu.z) * vt.z + tanhf(v.w + uu.w) * vt.w;
  s = waveAllSum(s);
  if (lane == 0) sP[b * LPn + p] = s;
}

// -------- softmax over 2048, one block per b --------
__global__ __launch_bounds__(256) void k_softmax(const float* __restrict__ sP,
                                                 float* __restrict__ out) {
  int b = blockIdx.x, tid = threadIdx.x;
  int lane = tid & 63, wid = tid >> 6;
  __shared__ float red[4];
  float v[8];
  float m = -1e30f;
  #pragma unroll
  for (int i = 0; i < 8; ++i) {
    v[i] = sP[b * LPn + i * 256 + tid];
    m = fmaxf(m, v[i]);
  }
  m = waveAllMax(m);
  if (lane == 0) red[wid] = m;
  __syncthreads();
  m = fmaxf(fmaxf(red[0], red[1]), fmaxf(red[2], red[3]));
  float s = 0.f;
  #pragma unroll
  for (int i = 0; i < 8; ++i) { v[i] = expf(v[i] - m); s += v[i]; }
  s = waveAllSum(s);
  __syncthreads();
  if (lane == 0) red[wid] = s;
  __syncthreads();
  s = red[0] + red[1] + red[2] + red[3];
  float inv = 1.0f / s;
  #pragma unroll
  for (int i = 0; i < 8; ++i) out[b * LPn + i * 256 + tid] = v[i] * inv;
}

// -------- ct[b][d] = sum_p aP[b][p]*passEnc[p,b,d], float4, grid (64,16) ----
__global__ __launch_bounds__(256) void k_ct(const float* __restrict__ aP,
                                            const float* __restrict__ passEnc,
                                            float* __restrict__ ct) {
  int b = blockIdx.x, pc = blockIdx.y, tid = threadIdx.x;
  int dg = tid & 127;   // float4 slot
  int pg = tid >> 7;    // 0,1
  f32x4 acc = (f32x4)0.f;
  for (int pp = 0; pp < 64; ++pp) {
    int p = pc * 128 + pg * 64 + pp;
    float a = aP[b * LPn + p];
    acc += a * *(const f32x4*)&passEnc[((size_t)p * Bn + b) * D2H + dg * 4];
  }
  __shared__ f32x4 sacc[256];
  sacc[tid] = acc;
  __syncthreads();
  if (pg == 0) {
    acc += sacc[tid + 128];
    float* dst = &ct[b * D2H + dg * 4];
    atomicAdd(dst + 0, acc[0]);
    atomicAdd(dst + 1, acc[1]);
    atomicAdd(dst + 2, acc[2]);
    atomicAdd(dst + 3, acc[3]);
  }
}

// -------- fused GRU: gi, gh, gates -> rQ2.  grid (64, 2) --------
__global__ __launch_bounds__(256) void k_gru(const float* __restrict__ rQ,
                                             const float* __restrict__ ct,
                                             const float* __restrict__ wih,
                                             const float* __restrict__ whh,
                                             const float* __restrict__ bih,
                                             const float* __restrict__ bhh,
                                             float* __restrict__ rQ2) {
  int m = blockIdx.x;
  int j = blockIdx.y * 256 + threadIdx.x;  // 0..511
  __shared__ float sx[D2H], sh[D2H];
  sx[threadIdx.x]       = rQ[m * D2H + threadIdx.x];
  sx[threadIdx.x + 256] = rQ[m * D2H + threadIdx.x + 256];
  sh[threadIdx.x]       = ct[m * D2H + threadIdx.x];
  sh[threadIdx.x + 256] = ct[m * D2H + threadIdx.x + 256];
  __syncthreads();
  float gr = bih[j], gz = bih[512 + j], gn = bih[1024 + j];
  float hr = bhh[j], hz = bhh[512 + j], hn = bhh[1024 + j];
  const float* wr0 = wih + (size_t)j * 512;
  const float* wr1 = wih + (size_t)(512 + j) * 512;
  const float* wr2 = wih + (size_t)(1024 + j) * 512;
  const float* vr0 = whh + (size_t)j * 512;
  const float* vr1 = whh + (size_t)(512 + j) * 512;
  const float* vr2 = whh + (size_t)(1024 + j) * 512;
  for (int k4 = 0; k4 < 128; ++k4) {
    f32x4 x = *(const f32x4*)&sx[k4 * 4];
    f32x4 h = *(const f32x4*)&sh[k4 * 4];
    f32x4 w0 = *(const f32x4*)&wr0[k4 * 4];
    f32x4 w1 = *(const f32x4*)&wr1[k4 * 4];
    f32x4 w2 = *(const f32x4*)&wr2[k4 * 4];
    f32x4 v0 = *(const f32x4*)&vr0[k4 * 4];
    f32x4 v1 = *(const f32x4*)&vr1[k4 * 4];
    f32x4 v2 = *(const f32x4*)&vr2[k4 * 4];
    #pragma unroll
    for (int e = 0; e < 4; ++e) {
      gr += w0[e] * x[e]; gz += w1[e] * x[e]; gn += w2[e] * x[e];
      hr += v0[e] * h[e]; hz += v1[e] * h[e]; hn += v2[e] * h[e];
    }
  }
  float r = 1.f / (1.f + expf(-(gr + hr)));
  float z = 1.f / (1.f + expf(-(gz + hz)));
  float nn = tanhf(gn + r * hn);
  rQ2[m * D2H + j] = (1.f - z) * nn + z * sh[j];
}

// -------- u2[m][n] = Wah[n] . rQ2[m] + Wah_b[n], grid 64 --------
__global__ __launch_bounds__(256) void k_u2(const float* __restrict__ rQ2,
                                            const float* __restrict__ Wah,
                                            const float* __restrict__ Wah_b,
                                            float* __restrict__ u2) {
  int m = blockIdx.x, n = threadIdx.x;
  __shared__ float s_r[D2H];
  s_r[n]       = rQ2[m * D2H + n];
  s_r[n + 256] = rQ2[m * D2H + n + 256];
  __syncthreads();
  float acc = Wah_b[n];
  const float* wr = Wah + (size_t)n * 512;
  for (int k4 = 0; k4 < 128; ++k4) {
    f32x4 wv = *(const f32x4*)&wr[k4 * 4];
    f32x4 rv = *(const f32x4*)&s_r[k4 * 4];
    acc += wv[0] * rv[0] + wv[1] * rv[1] + wv[2] * rv[2] + wv[3] * rv[3];
  }
  u2[m * Hn + n] = acc;
}

extern "C" void kernel_launch(void* const* d_in, const int* in_sizes, int n_in,
                              void* d_out, int out_size, void* d_ws, size_t ws_size,
                              hipStream_t stream) {
  const float* passEnc  = (const float*)d_in[0];
  const float* quesEnc  = (const float*)d_in[1];
  const float* WQu_W    = (const float*)d_in[2];
  const float* WQu_b    = (const float*)d_in[3];
  const float* WQv_W    = (const float*)d_in[4];
  const float* WQv_b    = (const float*)d_in[5];
  const float* WPh_W    = (const float*)d_in[6];
  const float* WPh_b    = (const float*)d_in[7];
  const float* Wah_W    = (const float*)d_in[8];
  const float* Wah_b    = (const float*)d_in[9];
  const float* Vt1      = (const float*)d_in[10];
  const float* Vt2      = (const float*)d_in[11];
  const float* VQr      = (const float*)d_in[12];
  const float* gru_wih  = (const float*)d_in[13];
  const float* gru_whh  = (const float*)d_in[14];
  const float* gru_bih  = (const float*)d_in[15];
  const float* gru_bhh  = (const float*)d_in[16];
  float* out = (float*)d_out;

  float* ws = (float*)d_ws;
  float* passP = ws;                    // 33554432
  float* v2    = ws + 33554432;         // 256
  float* rQ    = v2 + 256;              // 32768
  float* u1    = rQ + 32768;            // 16384
  float* u2    = u1 + 16384;            // 16384
  float* sP    = u2 + 16384;            // 131072
  float* ct    = sP + 131072;           // 32768
  float* rQ2   = ct + 32768;            // 32768
  float* sQ    = rQ2 + 32768;           // 4096
  short* wqu2  = (short*)(sQ + 4096);   // 131072 shorts
  short* wph2  = wqu2 + 131072;         // 131072 shorts

  k_wcvt<<<128, 256, 0, stream>>>(WQu_W, WPh_W, wqu2, wph2);
  k_v2<<<1, 256, 0, stream>>>(VQr, WQv_W, WQv_b, v2);

  // question path: fused G1+sQ (no C store), softmax+rQ+u1
  k_mfma_fused<<<LQn, 256, 0, stream>>>(quesEnc, wqu2, WQu_b, v2, Vt1,
                                        nullptr, sQ, 0, LQn);
  k_rq_u1<<<Bn, 256, 0, stream>>>(sQ, quesEnc, Wah_W, Wah_b, rQ, u1);

  // passage: fused passP + sP1
  k_mfma_fused<<<LPn, 256, 0, stream>>>(passEnc, wph2, WPh_b, u1, Vt2,
                                        passP, sP, Hn, LPn);
  k_softmax<<<Bn, 256, 0, stream>>>(sP, out);  // aP1

  hipMemsetAsync(ct, 0, Bn * D2H * sizeof(float), stream);
  k_ct<<<dim3(Bn, 16), 256, 0, stream>>>(out, passEnc, ct);

  k_gru<<<dim3(Bn, 2), 256, 0, stream>>>(rQ, ct, gru_wih, gru_whh,
                                         gru_bih, gru_bhh, rQ2);
  k_u2<<<Bn, 256, 0, stream>>>(rQ2, Wah_W, Wah_b, u2);

  k_sp<<<LPn * Bn / 4, 256, 0, stream>>>(passP, u2, Vt2, sP);
  k_softmax<<<Bn, 256, 0, stream>>>(sP, out + Bn * LPn);  // aP2
}